// Round 1
// baseline (410.373 us; speedup 1.0000x reference)
//
#include <hip/hip_runtime.h>
#include <stdint.h>

// Try modern-JAX partitionable threefry first (default since jax 0.4.30).
// If absmax fails at ~0.1-0.4, flip to 0 (original iota-split path).
#define PARTITIONABLE 1

#define ET 128
#define ES 16
#define KSTEPS 3

__host__ __device__ inline void tf2x32(uint32_t k0, uint32_t k1,
                                       uint32_t& x0, uint32_t& x1) {
  uint32_t ks2 = k0 ^ k1 ^ 0x1BD11BDAu;
  x0 += k0; x1 += k1;
#define TF_ROT(r) { x0 += x1; x1 = (x1 << (r)) | (x1 >> (32 - (r))); x1 ^= x0; }
  TF_ROT(13) TF_ROT(15) TF_ROT(26) TF_ROT(6)
  x0 += k1;  x1 += ks2 + 1u;
  TF_ROT(17) TF_ROT(29) TF_ROT(16) TF_ROT(24)
  x0 += ks2; x1 += k0 + 2u;
  TF_ROT(13) TF_ROT(15) TF_ROT(26) TF_ROT(6)
  x0 += k0;  x1 += k1 + 3u;
  TF_ROT(17) TF_ROT(29) TF_ROT(16) TF_ROT(24)
  x0 += k1;  x1 += ks2 + 4u;
  TF_ROT(13) TF_ROT(15) TF_ROT(26) TF_ROT(6)
  x0 += ks2; x1 += k0 + 5u;
#undef TF_ROT
}

__device__ inline float gumbel_bits(uint32_t s0, uint32_t s1, uint32_t j,
                                    uint32_t half) {
  uint32_t x0, x1, bits;
#if PARTITIONABLE
  x0 = 0u; x1 = j;
  tf2x32(s0, s1, x0, x1);
  bits = x0 ^ x1;
#else
  if (j < half) { x0 = j; x1 = j + half; } else { x0 = j - half; x1 = j; }
  tf2x32(s0, s1, x0, x1);
  bits = (j < half) ? x0 : x1;
#endif
  // jax.random.uniform(minval=tiny, maxval=1): (1-tiny)==1 in f32 -> u = f + tiny
  float f = __uint_as_float((bits >> 9) | 0x3F800000u) - 1.0f;
  const float TINY = 1.17549435e-38f;
  float u = fmaxf(TINY, f + TINY);
  return -logf(-logf(u));
}

// acc layout (doubles): [0]=sum_w [1]=sum_klw [2..129]=t_counts [130..257]=s_counts
__launch_bounds__(256)
__global__ void sample_kernel(const float* __restrict__ tg,
                              const float* __restrict__ sg,
                              const int* __restrict__ am,
                              double* __restrict__ acc,
                              uint32_t s00, uint32_t s01,
                              uint32_t s10, uint32_t s11,
                              uint32_t s20, uint32_t s21,
                              int N, uint32_t half) {
  __shared__ float lds_t[ES], lds_s[ES];
  __shared__ float lds_w, lds_kl;
  if (threadIdx.x < ES) { lds_t[threadIdx.x] = 0.f; lds_s[threadIdx.x] = 0.f; }
  if (threadIdx.x == 0) { lds_w = 0.f; lds_kl = 0.f; }
  __syncthreads();

  const int wave = blockIdx.x * (blockDim.x >> 6) + (threadIdx.x >> 6);
  const int lane = threadIdx.x & 63;

  if (wave < N) {
    const int n = wave;
    float p0 = tg[(size_t)n * ET + lane];
    float p1 = tg[(size_t)n * ET + lane + 64];
    const uint32_t subs[KSTEPS][2] = {{s00, s01}, {s10, s11}, {s20, s21}};
    int idxk[KSTEPS];
    float wk[KSTEPS];

#pragma unroll
    for (int k = 0; k < KSTEPS; ++k) {
      uint32_t j0 = (uint32_t)n * ET + (uint32_t)lane;
      float g0 = gumbel_bits(subs[k][0], subs[k][1], j0, half);
      float g1 = gumbel_bits(subs[k][0], subs[k][1], j0 + 64u, half);
      float v0 = g0 + logf(p0);
      float v1 = g1 + logf(p1);
      float v = v0; int bi = lane;
      if (v1 > v) { v = v1; bi = lane + 64; }  // tie -> lower index (argmax first-hit)
#pragma unroll
      for (int off = 32; off; off >>= 1) {
        float ov = __shfl_xor(v, off);
        int   oi = __shfl_xor(bi, off);
        if (ov > v || (ov == v && oi < bi)) { v = ov; bi = oi; }
      }
      float w0b = __shfl(p0, bi & 63);
      float w1b = __shfl(p1, bi & 63);
      wk[k] = (bi < 64) ? w0b : w1b;   // importance weight BEFORE damping
      idxk[k] = bi;
      if (lane == (bi & 63)) { if (bi < 64) p0 *= 0.5f; else p1 *= 0.5f; }
      float t = p0 + p1;
#pragma unroll
      for (int off = 32; off; off >>= 1) t += __shfl_xor(t, off);
      p0 /= t; p1 /= t;
    }

    if (lane == 0) {
      float vm = (float)am[n];
      float sw = 0.f, skl = 0.f;
#pragma unroll
      for (int k = 0; k < KSTEPS; ++k) {
        float ws = wk[k] * vm;
        sw += ws;
        int idx = idxk[k];
        if ((idx & 7) == 0) {               // idx % carry == 0 (carry = 8)
          int sidx = idx >> 3;              // already in [0,15]
          skl += -logf(sg[(size_t)n * ES + sidx]) * ws;
        }
        if (idx < ES) {                     // in_range for coverage counts
          atomicAdd(&lds_t[idx], ws);
          atomicAdd(&lds_s[idx], sg[(size_t)n * ES + idx] * vm);
        }
      }
      atomicAdd(&lds_w, sw);
      atomicAdd(&lds_kl, skl);
    }
  }
  __syncthreads();

  if (threadIdx.x == 0) {
    atomicAdd(&acc[0], (double)lds_w);
    atomicAdd(&acc[1], (double)lds_kl);
  }
  if (threadIdx.x < ES) {
    atomicAdd(&acc[2 + threadIdx.x], (double)lds_t[threadIdx.x]);
    atomicAdd(&acc[2 + 128 + threadIdx.x], (double)lds_s[threadIdx.x]);
  }
}

__global__ void finalize_kernel(const double* __restrict__ acc,
                                float* __restrict__ out) {
  if (threadIdx.x != 0 || blockIdx.x != 0) return;
  const double EPSD = 1e-8;
  double sum_w = acc[0], sum_kl = acc[1];
  double feat = sum_kl / fmax(sum_w, EPSD);
  double tsum = 0.0, ssum = 0.0;
  for (int i = 0; i < 128; ++i) { tsum += acc[2 + i]; ssum += acc[130 + i]; }
  double ta2 = 0.0, sa2 = 0.0;
  for (int i = 0; i < 128; ++i) {
    ta2 += acc[2 + i] / tsum + EPSD;
    sa2 += acc[130 + i] / ssum + EPSD;
  }
  double cov = 0.0;
  for (int i = 0; i < 128; ++i) {
    double ta = (acc[2 + i] / tsum + EPSD) / ta2;
    double sa = (acc[130 + i] / ssum + EPSD) / sa2;
    cov += ta * (log(ta) - log(sa));
  }
  cov /= 128.0;
  out[0] = (float)(feat + 0.5 * cov);
}

extern "C" void kernel_launch(void* const* d_in, const int* in_sizes, int n_in,
                              void* d_out, int out_size, void* d_ws, size_t ws_size,
                              hipStream_t stream) {
  const float* tg = (const float*)d_in[0];
  const float* sg = (const float*)d_in[1];
  const int*   am = (const int*)d_in[4];
  const int N = in_sizes[4];  // B*S tokens

  // Host-side key chain: key = jax.random.key(42) -> data (0, 42)
  uint32_t key0 = 0u, key1 = 42u;
  uint32_t subs[KSTEPS][2];
  for (int k = 0; k < KSTEPS; ++k) {
#if PARTITIONABLE
    // foldlike split: keys[i] = threefry(key, hi=0, lo=i); new=keys[0], sub=keys[1]
    uint32_t a0 = 0u, a1 = 0u; tf2x32(key0, key1, a0, a1);
    uint32_t b0 = 0u, b1 = 1u; tf2x32(key0, key1, b0, b1);
    subs[k][0] = b0; subs[k][1] = b1;
    key0 = a0; key1 = a1;
#else
    // original split: counts iota(4) halved -> blocks (0,2),(1,3)
    uint32_t c00 = 0u, c01 = 2u; tf2x32(key0, key1, c00, c01);
    uint32_t c10 = 1u, c11 = 3u; tf2x32(key0, key1, c10, c11);
    subs[k][0] = c01; subs[k][1] = c11;  // sub = (out1_b0, out1_b1)
    uint32_t nk0 = c00, nk1 = c10;       // key = (out0_b0, out0_b1)
    key0 = nk0; key1 = nk1;
#endif
  }

  const uint32_t half = (uint32_t)(((uint64_t)N * ET) / 2);
  double* acc = (double*)d_ws;
  hipMemsetAsync(d_ws, 0, 258 * sizeof(double), stream);

  const int waves_per_block = 4;
  const int blocks = (N + waves_per_block - 1) / waves_per_block;
  sample_kernel<<<blocks, 256, 0, stream>>>(
      tg, sg, am, acc,
      subs[0][0], subs[0][1], subs[1][0], subs[1][1], subs[2][0], subs[2][1],
      N, half);
  finalize_kernel<<<1, 64, 0, stream>>>(acc, (float*)d_out);
}

// Round 2
// 89.305 us; speedup vs baseline: 4.5952x; 4.5952x over previous
//
#include <hip/hip_runtime.h>
#include <stdint.h>

#define ET 128
#define ES 16
#define KSTEPS 3
#define ACC_STRIDE 258   // doubles per replica: [0]=sum_w [1]=sum_klw [2..17]=t_counts [18..33]=s_counts (rest pad)
#define ACC_USED 34
#define MAX_REPL 64

__host__ __device__ inline void tf2x32(uint32_t k0, uint32_t k1,
                                       uint32_t& x0, uint32_t& x1) {
  uint32_t ks2 = k0 ^ k1 ^ 0x1BD11BDAu;
  x0 += k0; x1 += k1;
#define TF_ROT(r) { x0 += x1; x1 = (x1 << (r)) | (x1 >> (32 - (r))); x1 ^= x0; }
  TF_ROT(13) TF_ROT(15) TF_ROT(26) TF_ROT(6)
  x0 += k1;  x1 += ks2 + 1u;
  TF_ROT(17) TF_ROT(29) TF_ROT(16) TF_ROT(24)
  x0 += ks2; x1 += k0 + 2u;
  TF_ROT(13) TF_ROT(15) TF_ROT(26) TF_ROT(6)
  x0 += k0;  x1 += k1 + 3u;
  TF_ROT(17) TF_ROT(29) TF_ROT(16) TF_ROT(24)
  x0 += k1;  x1 += ks2 + 4u;
  TF_ROT(13) TF_ROT(15) TF_ROT(26) TF_ROT(6)
  x0 += ks2; x1 += k0 + 5u;
#undef TF_ROT
}

// partitionable threefry: bits for flat index j = fold(threefry(sub, (0, j)))
__device__ inline float gumbel_bits(uint32_t s0, uint32_t s1, uint32_t j) {
  uint32_t x0 = 0u, x1 = j;
  tf2x32(s0, s1, x0, x1);
  uint32_t bits = x0 ^ x1;
  float f = __uint_as_float((bits >> 9) | 0x3F800000u) - 1.0f;
  const float TINY = 1.17549435e-38f;
  float u = fmaxf(TINY, f + TINY);
  return -logf(-logf(u));
}

__launch_bounds__(256)
__global__ void sample_kernel(const float* __restrict__ tg,
                              const float* __restrict__ sg,
                              const int* __restrict__ am,
                              double* __restrict__ acc, int repl,
                              uint32_t s00, uint32_t s01,
                              uint32_t s10, uint32_t s11,
                              uint32_t s20, uint32_t s21,
                              int N, int total_waves) {
  __shared__ float lds_t[ES], lds_s[ES];
  __shared__ float lds_w[4], lds_kl[4];
  if (threadIdx.x < ES) { lds_t[threadIdx.x] = 0.f; lds_s[threadIdx.x] = 0.f; }
  __syncthreads();

  const int wslot = threadIdx.x >> 6;
  const int wid = blockIdx.x * 4 + wslot;
  const int lane = threadIdx.x & 63;
  const uint32_t subs[KSTEPS][2] = {{s00, s01}, {s10, s11}, {s20, s21}};
  const float LN2 = 0.69314718055994530942f;

  float sum_w = 0.f, sum_kl = 0.f;

  for (int n = wid; n < N; n += total_waves) {
    float p0 = tg[(size_t)n * ET + lane];
    float p1 = tg[(size_t)n * ET + lane + 64];
    float lp0 = logf(p0);
    float lp1 = logf(p1);
    float t = 1.0f;   // running norm of the (unnormalized) prob vector

#pragma unroll
    for (int k = 0; k < KSTEPS; ++k) {
      uint32_t j0 = (uint32_t)n * ET + (uint32_t)lane;
      float g0 = gumbel_bits(subs[k][0], subs[k][1], j0);
      float g1 = gumbel_bits(subs[k][0], subs[k][1], j0 + 64u);
      // argmax(g + log(p/t)) == argmax(g + log p): skip renormalization entirely
      float v0 = g0 + lp0;
      float v1 = g1 + lp1;
      float v = v0; int bi = lane;
      if (v1 > v) { v = v1; bi = lane + 64; }
#pragma unroll
      for (int off = 32; off; off >>= 1) {
        float ov = __shfl_xor(v, off);
        int   oi = __shfl_xor(bi, off);
        if (ov > v || (ov == v && oi < bi)) { v = ov; bi = oi; }
      }
      float w0b = __shfl(p0, bi & 63);
      float w1b = __shfl(p1, bi & 63);
      float w_abs = (bi < 64) ? w0b : w1b;   // unnormalized prob of sampled expert
      float wk = w_abs / t;                  // == renormalized prob (importance wt)

      if (lane == 0) {
        float vm = (float)am[n];
        float ws = wk * vm;
        sum_w += ws;
        if ((bi & 7) == 0)                   // idx % carry == 0 (carry = 8)
          sum_kl += -logf(sg[(size_t)n * ES + (bi >> 3)]) * ws;
        if (bi < ES) {
          atomicAdd(&lds_t[bi], ws);
          atomicAdd(&lds_s[bi], sg[(size_t)n * ES + bi] * vm);
        }
      }
      if (k < KSTEPS - 1) {
        if (lane == (bi & 63)) {
          if (bi < 64) { p0 *= 0.5f; lp0 -= LN2; }
          else         { p1 *= 0.5f; lp1 -= LN2; }
        }
        t -= 0.5f * w_abs;                   // new norm after damping
      }
    }
  }

  if (lane == 0) { lds_w[wslot] = sum_w; lds_kl[wslot] = sum_kl; }
  __syncthreads();

  double* slot = acc + (size_t)(blockIdx.x % repl) * ACC_STRIDE;
  if (threadIdx.x == 0) {
    atomicAdd(&slot[0], (double)(lds_w[0] + lds_w[1] + lds_w[2] + lds_w[3]));
    atomicAdd(&slot[1], (double)(lds_kl[0] + lds_kl[1] + lds_kl[2] + lds_kl[3]));
  }
  if (threadIdx.x < ES) {
    atomicAdd(&slot[2 + threadIdx.x], (double)lds_t[threadIdx.x]);
    atomicAdd(&slot[2 + ES + threadIdx.x], (double)lds_s[threadIdx.x]);
  }
}

__global__ void finalize_kernel(const double* __restrict__ acc, int repl,
                                float* __restrict__ out) {
  __shared__ double tot[ACC_USED];
  const int tid = threadIdx.x;
  if (tid < ACC_USED) {
    double s = 0.0;
    for (int r = 0; r < repl; ++r) s += acc[(size_t)r * ACC_STRIDE + tid];
    tot[tid] = s;
  }
  __syncthreads();
  if (tid != 0) return;

  const double EPSD = 1e-8;
  double feat = tot[1] / fmax(tot[0], EPSD);

  double tsum = 0.0, ssum = 0.0;
  for (int i = 0; i < ES; ++i) { tsum += tot[2 + i]; ssum += tot[2 + ES + i]; }
  double ta2 = 0.0, sa2 = 0.0;
  for (int i = 0; i < ES; ++i) {
    ta2 += tot[2 + i] / tsum + EPSD;
    sa2 += tot[2 + ES + i] / ssum + EPSD;
  }
  ta2 += (ET - ES) * EPSD;   // 112 zero bins contribute EPS each
  sa2 += (ET - ES) * EPSD;
  double cov = 0.0;
  for (int i = 0; i < ES; ++i) {
    double ta = (tot[2 + i] / tsum + EPSD) / ta2;
    double sa = (tot[2 + ES + i] / ssum + EPSD) / sa2;
    cov += ta * (log(ta) - log(sa));
  }
  {  // the 112 zero bins, closed-form
    double ta0 = EPSD / ta2, sa0 = EPSD / sa2;
    cov += (double)(ET - ES) * ta0 * (log(ta0) - log(sa0));
  }
  cov /= (double)ET;
  out[0] = (float)(feat + 0.5 * cov);
}

extern "C" void kernel_launch(void* const* d_in, const int* in_sizes, int n_in,
                              void* d_out, int out_size, void* d_ws, size_t ws_size,
                              hipStream_t stream) {
  const float* tg = (const float*)d_in[0];
  const float* sg = (const float*)d_in[1];
  const int*   am = (const int*)d_in[4];
  const int N = in_sizes[4];  // B*S tokens

  // Host-side key chain: key = jax.random.key(42); per step: foldlike split
  uint32_t key0 = 0u, key1 = 42u;
  uint32_t subs[KSTEPS][2];
  for (int k = 0; k < KSTEPS; ++k) {
    uint32_t a0 = 0u, a1 = 0u; tf2x32(key0, key1, a0, a1);  // new key
    uint32_t b0 = 0u, b1 = 1u; tf2x32(key0, key1, b0, b1);  // subkey
    subs[k][0] = b0; subs[k][1] = b1;
    key0 = a0; key1 = a1;
  }

  int repl = (int)(ws_size / (ACC_STRIDE * sizeof(double)));
  if (repl > MAX_REPL) repl = MAX_REPL;
  if (repl < 1) repl = 1;

  double* acc = (double*)d_ws;
  hipMemsetAsync(d_ws, 0, (size_t)repl * ACC_STRIDE * sizeof(double), stream);

  int blocks = 2048;
  if (blocks * 4 > N) blocks = (N + 3) / 4;
  const int total_waves = blocks * 4;

  sample_kernel<<<blocks, 256, 0, stream>>>(
      tg, sg, am, acc, repl,
      subs[0][0], subs[0][1], subs[1][0], subs[1][1], subs[2][0], subs[2][1],
      N, total_waves);
  finalize_kernel<<<1, 64, 0, stream>>>(acc, repl, (float*)d_out);
}

// Round 3
// 86.334 us; speedup vs baseline: 4.7533x; 1.0344x over previous
//
#include <hip/hip_runtime.h>
#include <stdint.h>

#define ET 128
#define ES 16
#define KSTEPS 3
#define ACC_STRIDE 258   // doubles per replica slot
#define ACC_USED 34      // [0]=sum_w [1]=sum_klw [2..17]=t_counts [18..33]=s_counts
#define MAX_REPL 64

__host__ __device__ inline void tf2x32(uint32_t k0, uint32_t k1,
                                       uint32_t& x0, uint32_t& x1) {
  uint32_t ks2 = k0 ^ k1 ^ 0x1BD11BDAu;
  x0 += k0; x1 += k1;
#define TF_ROT(r) { x0 += x1; x1 = (x1 << (r)) | (x1 >> (32 - (r))); x1 ^= x0; }
  TF_ROT(13) TF_ROT(15) TF_ROT(26) TF_ROT(6)
  x0 += k1;  x1 += ks2 + 1u;
  TF_ROT(17) TF_ROT(29) TF_ROT(16) TF_ROT(24)
  x0 += ks2; x1 += k0 + 2u;
  TF_ROT(13) TF_ROT(15) TF_ROT(26) TF_ROT(6)
  x0 += k0;  x1 += k1 + 3u;
  TF_ROT(17) TF_ROT(29) TF_ROT(16) TF_ROT(24)
  x0 += k1;  x1 += ks2 + 4u;
  TF_ROT(13) TF_ROT(15) TF_ROT(26) TF_ROT(6)
  x0 += ks2; x1 += k0 + 5u;
#undef TF_ROT
}

// partitionable threefry: uniform(0,1) sample for flat index j under subkey s
__device__ inline float unif01(uint32_t s0, uint32_t s1, uint32_t j) {
  uint32_t x0 = 0u, x1 = j;
  tf2x32(s0, s1, x0, x1);
  uint32_t bits = x0 ^ x1;
  float f = __uint_as_float((bits >> 9) | 0x3F800000u) - 1.0f;
  const float TINY = 1.17549435e-38f;
  return fmaxf(TINY, f + TINY);
}

__device__ inline float gumbelf(float u) {
  return -__logf(-__logf(u));   // argmax-only consumer: fast log is safe
}

// order-preserving float->u32, packed with (255-idx) so u64-max == argmax
// with lowest-index tie-break (matches jnp.argmax first-hit semantics)
__device__ inline unsigned long long argkey(float v, int idx) {
  uint32_t b = __float_as_uint(v);
  uint32_t u = b ^ (0x80000000u | (uint32_t)((int32_t)b >> 31));
  return ((unsigned long long)u << 32) | (uint32_t)(255 - idx);
}

__launch_bounds__(256)
__global__ void sample_kernel(const float* __restrict__ tg,
                              const float* __restrict__ sg,
                              const int* __restrict__ am,
                              double* __restrict__ acc, int repl,
                              uint32_t s00, uint32_t s01,
                              uint32_t s10, uint32_t s11,
                              uint32_t s20, uint32_t s21,
                              int N, int total_waves) {
  __shared__ float lds_t[ES], lds_s[ES];
  __shared__ float lds_w[4], lds_kl[4];
  if (threadIdx.x < ES) { lds_t[threadIdx.x] = 0.f; lds_s[threadIdx.x] = 0.f; }
  __syncthreads();

  const int wslot = threadIdx.x >> 6;
  const int wid = blockIdx.x * 4 + wslot;
  const int lane = threadIdx.x & 63;
  const float LN2 = 0.69314718055994530942f;

  float sum_w = 0.f, sum_kl = 0.f;

  for (int n = wid; n < N; n += total_waves) {
    const float* row = tg + (size_t)n * ET;
    float p0 = row[lane];
    float p1 = row[lane + 64];
    float vm = (float)am[n];

    // --- 6 independent threefry+gumbel streams: maximum ILP ---
    const uint32_t j0 = (uint32_t)n * ET + (uint32_t)lane;
    float u00 = unif01(s00, s01, j0), u01 = unif01(s00, s01, j0 + 64u);
    float u10 = unif01(s10, s11, j0), u11 = unif01(s10, s11, j0 + 64u);
    float u20 = unif01(s20, s21, j0), u21 = unif01(s20, s21, j0 + 64u);
    float lp0 = __logf(p0), lp1 = __logf(p1);
    float b0[KSTEPS] = {gumbelf(u00) + lp0, gumbelf(u10) + lp0, gumbelf(u20) + lp0};
    float b1[KSTEPS] = {gumbelf(u01) + lp1, gumbelf(u11) + lp1, gumbelf(u21) + lp1};

    float c0 = 0.f, c1 = 0.f;   // damp counts for this lane's two experts
    float t = 1.0f;             // running norm of the damped prob vector

#pragma unroll
    for (int k = 0; k < KSTEPS; ++k) {
      // score = gumbel + log(p * 2^-c / t); t uniform => drop; 2^-c via fma
      float v0 = fmaf(c0, -LN2, b0[k]);
      float v1 = fmaf(c1, -LN2, b1[k]);
      unsigned long long k0 = argkey(v0, lane);
      unsigned long long k1 = argkey(v1, lane + 64);
      unsigned long long key = (k1 > k0) ? k1 : k0;
#pragma unroll
      for (int off = 32; off; off >>= 1) {
        unsigned long long ok = __shfl_xor(key, off);
        if (ok > key) key = ok;
      }
      const int bi = 255 - (int)(key & 0xFFu);

      float w0b = __shfl(p0, bi & 63);
      float w1b = __shfl(p1, bi & 63);
      float w_abs = (bi < 64) ? w0b : w1b;   // current damped unnorm prob of winner

      if (lane == 0) {
        float ws = w_abs * __frcp_rn(t) * vm;   // renormalized importance weight
        sum_w += ws;
        if ((bi & 7) == 0)                       // teacher idx maps onto student grid
          sum_kl += -__logf(sg[(size_t)n * ES + (bi >> 3)]) * ws;
        if (bi < ES) {
          atomicAdd(&lds_t[bi], ws);
          atomicAdd(&lds_s[bi], sg[(size_t)n * ES + bi] * vm);
        }
      }
      if (k < KSTEPS - 1) {
        if (lane == (bi & 63)) {
          if (bi < 64) { p0 *= 0.5f; c0 += 1.f; }
          else         { p1 *= 0.5f; c1 += 1.f; }
        }
        t -= 0.5f * w_abs;   // norm after damping the winner
      }
    }
  }

  if (lane == 0) { lds_w[wslot] = sum_w; lds_kl[wslot] = sum_kl; }
  __syncthreads();

  double* slot = acc + (size_t)(blockIdx.x % repl) * ACC_STRIDE;
  if (threadIdx.x == 0) {
    atomicAdd(&slot[0], (double)(lds_w[0] + lds_w[1] + lds_w[2] + lds_w[3]));
    atomicAdd(&slot[1], (double)(lds_kl[0] + lds_kl[1] + lds_kl[2] + lds_kl[3]));
  }
  if (threadIdx.x < ES) {
    atomicAdd(&slot[2 + threadIdx.x], (double)lds_t[threadIdx.x]);
    atomicAdd(&slot[2 + ES + threadIdx.x], (double)lds_s[threadIdx.x]);
  }
}

__global__ void finalize_kernel(const double* __restrict__ acc, int repl,
                                float* __restrict__ out) {
  __shared__ double tot[ACC_USED];
  const int tid = threadIdx.x;
  if (tid < ACC_USED) {
    double s = 0.0;
    for (int r = 0; r < repl; ++r) s += acc[(size_t)r * ACC_STRIDE + tid];
    tot[tid] = s;
  }
  __syncthreads();
  if (tid != 0) return;

  const double EPSD = 1e-8;
  double feat = tot[1] / fmax(tot[0], EPSD);

  double tsum = 0.0, ssum = 0.0;
  for (int i = 0; i < ES; ++i) { tsum += tot[2 + i]; ssum += tot[2 + ES + i]; }
  double ta2 = 0.0, sa2 = 0.0;
  for (int i = 0; i < ES; ++i) {
    ta2 += tot[2 + i] / tsum + EPSD;
    sa2 += tot[2 + ES + i] / ssum + EPSD;
  }
  ta2 += (ET - ES) * EPSD;
  sa2 += (ET - ES) * EPSD;
  double cov = 0.0;
  for (int i = 0; i < ES; ++i) {
    double ta = (tot[2 + i] / tsum + EPSD) / ta2;
    double sa = (tot[2 + ES + i] / ssum + EPSD) / sa2;
    cov += ta * (log(ta) - log(sa));
  }
  {
    double ta0 = EPSD / ta2, sa0 = EPSD / sa2;
    cov += (double)(ET - ES) * ta0 * (log(ta0) - log(sa0));
  }
  cov /= (double)ET;
  out[0] = (float)(feat + 0.5 * cov);
}

extern "C" void kernel_launch(void* const* d_in, const int* in_sizes, int n_in,
                              void* d_out, int out_size, void* d_ws, size_t ws_size,
                              hipStream_t stream) {
  const float* tg = (const float*)d_in[0];
  const float* sg = (const float*)d_in[1];
  const int*   am = (const int*)d_in[4];
  const int N = in_sizes[4];  // B*S tokens

  // key chain: key = jax.random.key(42); per step foldlike split (partitionable)
  uint32_t key0 = 0u, key1 = 42u;
  uint32_t subs[KSTEPS][2];
  for (int k = 0; k < KSTEPS; ++k) {
    uint32_t a0 = 0u, a1 = 0u; tf2x32(key0, key1, a0, a1);  // new key
    uint32_t b0 = 0u, b1 = 1u; tf2x32(key0, key1, b0, b1);  // subkey
    subs[k][0] = b0; subs[k][1] = b1;
    key0 = a0; key1 = a1;
  }

  int repl = (int)(ws_size / (ACC_STRIDE * sizeof(double)));
  if (repl > MAX_REPL) repl = MAX_REPL;
  if (repl < 1) repl = 1;

  double* acc = (double*)d_ws;
  hipMemsetAsync(d_ws, 0, (size_t)repl * ACC_STRIDE * sizeof(double), stream);

  int blocks = 2048;
  if (blocks * 4 > N) blocks = (N + 3) / 4;
  const int total_waves = blocks * 4;

  sample_kernel<<<blocks, 256, 0, stream>>>(
      tg, sg, am, acc, repl,
      subs[0][0], subs[0][1], subs[1][0], subs[1][1], subs[2][0], subs[2][1],
      N, total_waves);
  finalize_kernel<<<1, 64, 0, stream>>>(acc, repl, (float*)d_out);
}